// Round 2
// baseline (371.072 us; speedup 1.0000x reference)
//
#include <hip/hip_runtime.h>
#include <float.h>

// Problem constants (match reference)
constexpr int H = 1024, W = 1024, C = 128, N_ITER = 8;
constexpr int TPB = 256;          // threads per block
constexpr int TILE = 32;          // 32x32 pixel tile per block
constexpr int PPT = 4;            // pixels (consecutive cols) per thread

// One block per 32x32 tile. Phase 1 (threads 0..127): exact triangle-inequality
// pruning — keep cluster c iff d_c(center) <= min_c d(center) + 2*r_tile + 1.
// r_tile = 15.5*sqrt(2); +1.0 margin covers fp32 rounding. Any cluster that can
// win the argmin (incl. the dist>=1-clamp tie region, since r >> 1) is kept.
// Compaction via ballot+prefix keeps ascending cluster order, so the strict-'<'
// first-index tie-break is identical to the full loop (round 1: absmax 0.0).
// Phase 2: argmin over ~3-6 candidates instead of 128 (~25x less VALU work).
__global__ __launch_bounds__(TPB) void kmeans_step(
    const float* __restrict__ cur,      // [C,2] current cluster coords
    const float* __restrict__ heatmap,  // [H,W]
    float* __restrict__ next)           // [C,2] output accumulators (pre-zeroed)
{
    __shared__ float2 cls[C];
    __shared__ float2 cand[C];
    __shared__ int    candIdx[C];
    __shared__ float  waveMin[2];
    __shared__ int    waveCnt[2];
    __shared__ float  acc[2 * C];       // 2*C == 256 == TPB

    const int tid   = threadIdx.x;
    const int tileR = (blockIdx.x >> 5) * TILE;
    const int tileC = (blockIdx.x & 31) * TILE;

    acc[tid] = 0.0f;

    // ---- phase 1a: distance from tile center, per-wave min (2 full waves) ----
    float dcen = 0.0f;
    if (tid < C) {
        const float2 cl = ((const float2*)cur)[tid];
        cls[tid] = cl;
        const float dxr = cl.x - ((float)tileR + 15.5f);
        const float dyc = cl.y - ((float)tileC + 15.5f);
        dcen = sqrtf(dxr * dxr + dyc * dyc);
        float m = dcen;
#pragma unroll
        for (int off = 32; off > 0; off >>= 1)
            m = fminf(m, __shfl_xor(m, off));
        if ((tid & 63) == 0) waveMin[tid >> 6] = m;
    }
    __syncthreads();

    // ---- phase 1b: keep-test + ballot prefix (order-preserving compaction) ----
    bool keep = false;
    int  pre  = 0;
    if (tid < C) {
        // 2*r_tile = 2*15.5*sqrt(2) = 43.84062; +1.0 fp32-rounding margin
        const float thr = fminf(waveMin[0], waveMin[1]) + 44.84062f;
        keep = (dcen <= thr);
        const unsigned long long mask = __ballot(keep);
        const int lane = tid & 63;
        pre = __popcll(mask & ((1ull << lane) - 1ull));
        if (lane == 0) waveCnt[tid >> 6] = __popcll(mask);
    }
    __syncthreads();
    if (keep) {
        const int pos = pre + ((tid >= 64) ? waveCnt[0] : 0);
        cand[pos]    = cls[tid];
        candIdx[pos] = tid;
    }
    __syncthreads();

    const int nCand = waveCnt[0] + waveCnt[1];   // >= 1 always (nearest kept)

    // ---- phase 2: pruned argmin over candidates ----
    const int   rowIn = tid >> 3;                         // 0..31
    const float fr    = (float)(tileR + rowIn);
    const int   col0  = tileC + (tid & 7) * PPT;
    const float4 h4   = *(const float4*)(heatmap + (size_t)(tileR + rowIn) * W + col0);

    float hval[PPT] = { h4.x, h4.y, h4.z, h4.w };
    float colf[PPT], best[PPT];
    int   bi[PPT];
#pragma unroll
    for (int p = 0; p < PPT; ++p) {
        colf[p] = (float)(col0 + p);
        best[p] = FLT_MAX;
        bi[p]   = 0;
    }

    for (int k = 0; k < nCand; ++k) {
        const float2 cl = cand[k];                        // wave-uniform broadcast
        const int    ci = candIdx[k];
        const float  dx  = fr - cl.x;
        const float  dx2 = dx * dx;                       // row-constant, reused x4
#pragma unroll
        for (int p = 0; p < PPT; ++p) {
            const float dy  = colf[p] - cl.y;
            const float d2  = fmaf(dy, dy, dx2);
            const float key = fmaxf(d2, 1.0f);            // clamp before compare
            const bool  lt  = key < best[p];              // strict <: first-index ties
            bi[p]   = lt ? ci  : bi[p];
            best[p] = lt ? key : best[p];
        }
    }

    // ---- epilogue: one sqrt per pixel, LDS scatter, 1 global atomic/slot ----
#pragma unroll
    for (int p = 0; p < PPT; ++p) {
        const float bd  = fmaxf(1.0f, sqrtf(best[p]));    // = max(1, sqrt(d2))
        const float wgt = hval[p] / bd;
        unsafeAtomicAdd(&acc[2 * bi[p] + 0], fr      * wgt);
        unsafeAtomicAdd(&acc[2 * bi[p] + 1], colf[p] * wgt);
    }
    __syncthreads();

    unsafeAtomicAdd(&next[tid], acc[tid]);
}

extern "C" void kernel_launch(void* const* d_in, const int* in_sizes, int n_in,
                              void* d_out, int out_size, void* d_ws, size_t ws_size,
                              hipStream_t stream) {
    const float* clusters = (const float*)d_in[0];  // [C,2] = 256 floats
    const float* heatmap  = (const float*)d_in[1];  // [H,W] = 1M floats
    float* out  = (float*)d_out;                    // [C,2] = 256 floats
    float* bufA = (float*)d_ws;
    float* bufB = bufA + 2 * C;

    // seed ping-pong with the input clusters
    hipMemcpyAsync(bufA, clusters, 2 * C * sizeof(float),
                   hipMemcpyDeviceToDevice, stream);

    const float* src = bufA;
    for (int it = 0; it < N_ITER; ++it) {
        float* dst = (it == N_ITER - 1) ? out : ((it & 1) ? bufA : bufB);
        hipMemsetAsync(dst, 0, 2 * C * sizeof(float), stream);
        kmeans_step<<<H, TPB, 0, stream>>>(src, heatmap, dst);
        src = dst;
    }
}

// Round 3
// 328.790 us; speedup vs baseline: 1.1286x; 1.1286x over previous
//
#include <hip/hip_runtime.h>
#include <float.h>

// Problem constants (match reference)
constexpr int H = 1024, W = 1024, C = 128, N_ITER = 8;
constexpr int TPB = 256;          // threads per block
constexpr int TILE = 32;          // 32x32 pixel tile per block
constexpr int PPT = 4;            // pixels (consecutive cols) per thread

// One block per 32x32 tile.
// Phase 1 (threads 0..127):
//   (a) exact triangle-inequality prune: keep c iff d_c(center) <= d_min + 2r + 1
//       (r = 15.5*sqrt(2); +1 covers the dist>=1 clamp region and fp32 rounding).
//   (b) exact coincident-cluster dedup: clusters with bit-identical coords give
//       identical distances everywhere; strict-'<' argmin always picks the
//       lowest index, so later duplicates can never win. This is essential:
//       from iter 3 on, segment_sum leaves 127 empty segments at exactly (0,0),
//       which defeats the distance prune alone (round-2 lesson).
//   Ballot+prefix compaction preserves ascending index -> tie-break unchanged.
// Phase 2: argmin over the ~2-6 surviving candidates.
// Epilogue: wave-uniform fast path (butterfly reduce + 1 atomic) when all lanes
// agree on the winner (the common case in degenerate iters), else per-lane LDS
// atomics; then 1 global atomic per slot per block.
// Also zeroes `zt` (next iteration's destination) - fuses the per-iter memsets.
__global__ __launch_bounds__(TPB) void kmeans_step(
    const float* __restrict__ cur,      // [C,2] current cluster coords
    const float* __restrict__ heatmap,  // [H,W]
    float* __restrict__ next,           // [C,2] output accumulators (pre-zeroed)
    float* __restrict__ zt)             // buffer to zero for the NEXT iter (may be null)
{
    __shared__ float2 cls[C];
    __shared__ float2 cand[C];
    __shared__ int    candIdx[C];
    __shared__ float  waveMin[2];
    __shared__ int    waveCnt[2];
    __shared__ float  acc[2 * C];       // 2*C == 256 == TPB

    const int tid   = threadIdx.x;
    const int tileR = (blockIdx.x >> 5) * TILE;
    const int tileC = (blockIdx.x & 31) * TILE;

    acc[tid] = 0.0f;
    if (zt) zt[tid] = 0.0f;             // idempotent redundant zeroing across blocks

    // ---- phase 1a: distance from tile center, per-wave min (2 full waves) ----
    float dcen = 0.0f;
    if (tid < C) {
        const float2 cl = ((const float2*)cur)[tid];
        cls[tid] = cl;
        const float dxr = cl.x - ((float)tileR + 15.5f);
        const float dyc = cl.y - ((float)tileC + 15.5f);
        dcen = sqrtf(dxr * dxr + dyc * dyc);
        float m = dcen;
#pragma unroll
        for (int off = 32; off > 0; off >>= 1)
            m = fminf(m, __shfl_xor(m, off));
        if ((tid & 63) == 0) waveMin[tid >> 6] = m;
    }
    __syncthreads();

    // ---- phase 1b: prune + dedup + ballot prefix (order-preserving) ----
    bool keep = false;
    int  pre  = 0;
    if (tid < C) {
        // 2*r_tile = 2*15.5*sqrt(2) = 43.84062; +1.0 clamp/rounding margin
        const float thr = fminf(waveMin[0], waveMin[1]) + 44.84062f;
        bool dup = false;
        const float2 me = cls[tid];
        for (int j = 0; j < tid; ++j) {         // exact dedup of coincident clusters
            const float2 o = cls[j];
            if (o.x == me.x && o.y == me.y) { dup = true; break; }
        }
        keep = (dcen <= thr) && !dup;
        const unsigned long long mask = __ballot(keep);
        const int lane = tid & 63;
        pre = __popcll(mask & ((1ull << lane) - 1ull));
        if (lane == 0) waveCnt[tid >> 6] = __popcll(mask);
    }
    __syncthreads();
    if (keep) {
        const int pos = pre + ((tid >= 64) ? waveCnt[0] : 0);
        cand[pos]    = cls[tid];
        candIdx[pos] = tid;
    }
    __syncthreads();

    const int nCand = waveCnt[0] + waveCnt[1];   // >= 1 always (nearest kept)

    // ---- phase 2: pruned argmin over candidates ----
    const int   rowIn = tid >> 3;                         // 0..31
    const float fr    = (float)(tileR + rowIn);
    const int   col0  = tileC + (tid & 7) * PPT;
    const float4 h4   = *(const float4*)(heatmap + (size_t)(tileR + rowIn) * W + col0);

    float hval[PPT] = { h4.x, h4.y, h4.z, h4.w };
    float colf[PPT], best[PPT];
    int   bi[PPT];
#pragma unroll
    for (int p = 0; p < PPT; ++p) {
        colf[p] = (float)(col0 + p);
        best[p] = FLT_MAX;
        bi[p]   = 0;
    }

    for (int k = 0; k < nCand; ++k) {
        const float2 cl = cand[k];                        // wave-uniform broadcast
        const int    ci = candIdx[k];
        const float  dx  = fr - cl.x;
        const float  dx2 = dx * dx;                       // row-constant, reused x4
#pragma unroll
        for (int p = 0; p < PPT; ++p) {
            const float dy  = colf[p] - cl.y;
            const float d2  = fmaf(dy, dy, dx2);
            const float key = fmaxf(d2, 1.0f);            // clamp before compare
            const bool  lt  = key < best[p];              // strict <: first-index ties
            bi[p]   = lt ? ci  : bi[p];
            best[p] = lt ? key : best[p];
        }
    }

    // ---- epilogue: 1 sqrt/pixel; wave-uniform reduce fast path; LDS scatter ----
#pragma unroll
    for (int p = 0; p < PPT; ++p) {
        const float bd  = fmaxf(1.0f, sqrtf(best[p]));    // = max(1, sqrt(d2))
        const float wgt = hval[p] / bd;
        float v0 = fr      * wgt;
        float v1 = colf[p] * wgt;
        const int b0 = __shfl(bi[p], 0);
        if (__ballot(bi[p] == b0) == 0xFFFFFFFFFFFFFFFFull) {
            // all 64 lanes agree: butterfly-sum, single atomic from lane 0
#pragma unroll
            for (int off = 32; off > 0; off >>= 1) {
                v0 += __shfl_xor(v0, off);
                v1 += __shfl_xor(v1, off);
            }
            if ((tid & 63) == 0) {
                unsafeAtomicAdd(&acc[2 * b0 + 0], v0);
                unsafeAtomicAdd(&acc[2 * b0 + 1], v1);
            }
        } else {
            unsafeAtomicAdd(&acc[2 * bi[p] + 0], v0);
            unsafeAtomicAdd(&acc[2 * bi[p] + 1], v1);
        }
    }
    __syncthreads();

    // one global atomic per accumulator slot per block (256 slots == TPB)
    unsafeAtomicAdd(&next[tid], acc[tid]);
}

extern "C" void kernel_launch(void* const* d_in, const int* in_sizes, int n_in,
                              void* d_out, int out_size, void* d_ws, size_t ws_size,
                              hipStream_t stream) {
    const float* clusters = (const float*)d_in[0];  // [C,2] = 256 floats
    const float* heatmap  = (const float*)d_in[1];  // [H,W] = 1M floats
    float* out = (float*)d_out;                     // [C,2] = 256 floats
    float* R[3] = { (float*)d_ws, (float*)d_ws + 2 * C, (float*)d_ws + 4 * C };

    // Rotation: iter i reads src(i), writes dst(i)=R[(i+1)%3] (pre-zeroed by
    // iter i-1), and zeroes zt(i)=dst(i+1). Iter 7 writes d_out; iter 6 zeroes it.
    hipMemsetAsync(R[1], 0, 2 * C * sizeof(float), stream);   // dst of iter 0

    const float* src = clusters;                    // iter 0 reads input directly
    for (int it = 0; it < N_ITER; ++it) {
        float* dst = (it == N_ITER - 1) ? out : R[(it + 1) % 3];
        float* zt;
        if (it == N_ITER - 2)      zt = out;                  // zero d_out for iter 7
        else if (it == N_ITER - 1) zt = nullptr;              // nothing left to zero
        else                       zt = R[(it + 2) % 3];      // dst of iter i+1
        kmeans_step<<<H, TPB, 0, stream>>>(src, heatmap, dst, zt);
        src = dst;
    }
}

// Round 4
// 158.306 us; speedup vs baseline: 2.3440x; 2.0769x over previous
//
#include <hip/hip_runtime.h>
#include <float.h>

// Problem constants (match reference)
constexpr int H = 1024, W = 1024, C = 128, N_ITER = 8;
constexpr int TPB = 256;          // threads per block
constexpr int TILE = 32;          // 32x32 pixel tile per block
constexpr int PPT = 4;            // pixels (consecutive cols) per thread
constexpr int K = 32;             // atomic shards (contention depth 1024/K = 32)
constexpr int SLOTS = 2 * C;      // 256 accumulator slots

// Round-3 lesson: the kernel was atomic-contention-bound, not VALU-bound.
// 1024 blocks x 256 lanes of device-scope fp32 RMW onto one 1KB buffer =
// depth-1024 serialized RMW per address ~= 43us. Fix: shard the target 32-way
// (block -> shard blockIdx&31), and let the NEXT kernel sum the shards.
//
// One block per 32x32 tile.
// Phase 0: reconstruct cluster coords = sum of prev iteration's 32 shards
//          (iter 0 reads the input directly).
// Phase 1 (threads 0..127):
//   (a) exact triangle-inequality prune: keep c iff d_c(center) <= d_min + 2r + 1.
//   (b) exact coincident-cluster dedup (strict-'<' argmin -> only the lowest
//       index of a coincident set can win). Essential: from iter 3 on,
//       segment_sum leaves ~127 empty segments at exactly (0,0).
//   Ballot+prefix compaction preserves ascending index -> tie-break unchanged.
// Phase 2: argmin over the ~2-6 surviving candidates.
// Epilogue: wave-uniform fast path (butterfly + 1 atomic) else per-lane LDS
// atomics; then ONE global atomic per nonzero slot per block into this
// block's shard (skip acc==0: contributions are >=+0.0, no -0.0 hazard).
__global__ __launch_bounds__(TPB) void kmeans_step(
    const float* __restrict__ cur0,        // [SLOTS] input clusters (iter 0 only)
    const float* __restrict__ prevShards,  // [K][SLOTS] prev iter shards (null on iter 0)
    const float* __restrict__ heatmap,     // [H,W]
    float* __restrict__ outShards)         // [K][SLOTS] this iter's shards (pre-zeroed)
{
    __shared__ float2 cls[C];              // aliased as float[SLOTS]
    __shared__ float2 cand[C];
    __shared__ int    candIdx[C];
    __shared__ float  waveMin[2];
    __shared__ int    waveCnt[2];
    __shared__ float  acc[SLOTS];          // SLOTS == 256 == TPB

    const int tid   = threadIdx.x;
    const int tileR = (blockIdx.x >> 5) * TILE;
    const int tileC = (blockIdx.x & 31) * TILE;

    acc[tid] = 0.0f;

    // ---- phase 0: materialize current cluster coords into LDS ----
    float coord;
    if (prevShards) {
        float s = 0.0f;
#pragma unroll
        for (int k = 0; k < K; ++k) s += prevShards[k * SLOTS + tid];
        coord = s;
    } else {
        coord = cur0[tid];
    }
    ((float*)cls)[tid] = coord;
    __syncthreads();

    // ---- phase 1a: distance from tile center, per-wave min (2 full waves) ----
    float dcen = 0.0f;
    if (tid < C) {
        const float2 cl = cls[tid];
        const float dxr = cl.x - ((float)tileR + 15.5f);
        const float dyc = cl.y - ((float)tileC + 15.5f);
        dcen = sqrtf(dxr * dxr + dyc * dyc);
        float m = dcen;
#pragma unroll
        for (int off = 32; off > 0; off >>= 1)
            m = fminf(m, __shfl_xor(m, off));
        if ((tid & 63) == 0) waveMin[tid >> 6] = m;
    }
    __syncthreads();

    // ---- phase 1b: prune + dedup + ballot prefix (order-preserving) ----
    bool keep = false;
    int  pre  = 0;
    if (tid < C) {
        // 2*r_tile = 2*15.5*sqrt(2) = 43.84062; +1.0 clamp/rounding margin
        const float thr = fminf(waveMin[0], waveMin[1]) + 44.84062f;
        bool dup = false;
        const float2 me = cls[tid];
        for (int j = 0; j < tid; ++j) {       // exact dedup of coincident clusters
            const float2 o = cls[j];
            if (o.x == me.x && o.y == me.y) { dup = true; break; }
        }
        keep = (dcen <= thr) && !dup;
        const unsigned long long mask = __ballot(keep);
        const int lane = tid & 63;
        pre = __popcll(mask & ((1ull << lane) - 1ull));
        if (lane == 0) waveCnt[tid >> 6] = __popcll(mask);
    }
    __syncthreads();
    if (keep) {
        const int pos = pre + ((tid >= 64) ? waveCnt[0] : 0);
        cand[pos]    = cls[tid];
        candIdx[pos] = tid;
    }
    __syncthreads();

    const int nCand = waveCnt[0] + waveCnt[1];   // >= 1 always (nearest kept)

    // ---- phase 2: pruned argmin over candidates ----
    const int   rowIn = tid >> 3;                         // 0..31
    const float fr    = (float)(tileR + rowIn);
    const int   col0  = tileC + (tid & 7) * PPT;
    const float4 h4   = *(const float4*)(heatmap + (size_t)(tileR + rowIn) * W + col0);

    float hval[PPT] = { h4.x, h4.y, h4.z, h4.w };
    float colf[PPT], best[PPT];
    int   bi[PPT];
#pragma unroll
    for (int p = 0; p < PPT; ++p) {
        colf[p] = (float)(col0 + p);
        best[p] = FLT_MAX;
        bi[p]   = 0;
    }

    for (int k = 0; k < nCand; ++k) {
        const float2 cl = cand[k];                        // wave-uniform broadcast
        const int    ci = candIdx[k];
        const float  dx  = fr - cl.x;
        const float  dx2 = dx * dx;                       // row-constant, reused x4
#pragma unroll
        for (int p = 0; p < PPT; ++p) {
            const float dy  = colf[p] - cl.y;
            const float d2  = fmaf(dy, dy, dx2);
            const float key = fmaxf(d2, 1.0f);            // clamp before compare
            const bool  lt  = key < best[p];              // strict <: first-index ties
            bi[p]   = lt ? ci  : bi[p];
            best[p] = lt ? key : best[p];
        }
    }

    // ---- epilogue: 1 sqrt/pixel; wave-uniform reduce fast path; LDS scatter ----
#pragma unroll
    for (int p = 0; p < PPT; ++p) {
        const float bd  = fmaxf(1.0f, sqrtf(best[p]));    // = max(1, sqrt(d2))
        const float wgt = hval[p] / bd;
        float v0 = fr      * wgt;
        float v1 = colf[p] * wgt;
        const int b0 = __shfl(bi[p], 0);
        if (__ballot(bi[p] == b0) == 0xFFFFFFFFFFFFFFFFull) {
            // all 64 lanes agree: butterfly-sum, single atomic from lane 0
#pragma unroll
            for (int off = 32; off > 0; off >>= 1) {
                v0 += __shfl_xor(v0, off);
                v1 += __shfl_xor(v1, off);
            }
            if ((tid & 63) == 0) {
                unsafeAtomicAdd(&acc[2 * b0 + 0], v0);
                unsafeAtomicAdd(&acc[2 * b0 + 1], v1);
            }
        } else {
            unsafeAtomicAdd(&acc[2 * bi[p] + 0], v0);
            unsafeAtomicAdd(&acc[2 * bi[p] + 1], v1);
        }
    }
    __syncthreads();

    // one global atomic per NONZERO slot into this block's shard.
    // (contributions are all >= +0.0 and the shard is pre-zeroed to +0.0,
    //  so skipping +0.0 adds is exact.)
    const float a = acc[tid];
    if (a != 0.0f)
        unsafeAtomicAdd(&outShards[(blockIdx.x & (K - 1)) * SLOTS + tid], a);
}

// Sum the last iteration's shards into d_out. One block.
__global__ __launch_bounds__(SLOTS) void kmeans_finalize(
    const float* __restrict__ shards,      // [K][SLOTS]
    float* __restrict__ out)               // [SLOTS]
{
    const int tid = threadIdx.x;
    float s = 0.0f;
#pragma unroll
    for (int k = 0; k < K; ++k) s += shards[k * SLOTS + tid];
    out[tid] = s;
}

extern "C" void kernel_launch(void* const* d_in, const int* in_sizes, int n_in,
                              void* d_out, int out_size, void* d_ws, size_t ws_size,
                              hipStream_t stream) {
    const float* clusters = (const float*)d_in[0];  // [C,2] = 256 floats
    const float* heatmap  = (const float*)d_in[1];  // [H,W] = 1M floats
    float* out = (float*)d_out;                     // [C,2] = 256 floats

    // d_ws layout: 8 per-iteration shard buffers, each [K][SLOTS] floats.
    float* shards = (float*)d_ws;                   // 8 * 32 * 256 * 4B = 256 KB
    const size_t perIter = (size_t)K * SLOTS;

    // zero ALL shard buffers once (harness re-poisons d_ws before every launch)
    hipMemsetAsync(shards, 0, N_ITER * perIter * sizeof(float), stream);

    for (int it = 0; it < N_ITER; ++it) {
        const float* prev = (it == 0) ? nullptr : (shards + (it - 1) * perIter);
        float* dst = shards + it * perIter;
        kmeans_step<<<H, TPB, 0, stream>>>(clusters, prev, heatmap, dst);
    }
    kmeans_finalize<<<1, SLOTS, 0, stream>>>(shards + (N_ITER - 1) * perIter, out);
}